// Round 18
// baseline (77.574 us; speedup 1.0000x reference)
//
#include <hip/hip_runtime.h>

typedef float v4f __attribute__((ext_vector_type(4)));

// R17 structure + counted-wait chunk pipeline:
//  - raw s_barrier with lgkmcnt(0) only (global reg-loads stay in flight across
//    barriers; hipcc's __syncthreads would drain vmcnt(0) every chunk)
//  - chunk i+1 regs->LDS write at iter i (loads issued at iter i-1: latency
//    hidden under a full iteration), chunk i+2 loads issued at iter i
//  - all 512 threads issue loads (3 x v4f each); tid<192 reduce; 192..383 accum
//  - xb stride 260 (kills 4-way accum conflicts); linear stage buf (2-way reads, free)
__global__ __launch_bounds__(512, 4) void k_fused9(
    const float* __restrict__ x,
    const float* __restrict__ wsq, const float* __restrict__ bsq,
    const float* __restrict__ gamma, const float* __restrict__ beta,
    const float* __restrict__ rmean, const float* __restrict__ rvar,
    const float* __restrict__ wc1, const float* __restrict__ bc1,
    const float* __restrict__ wex, const float* __restrict__ bex,
    float* __restrict__ out)
{
    __shared__ v4f   buf[2][1200];    // 38,400 B linear chunk stage (16 ch x 300 f)
    __shared__ float xb[12 * 260];    // frame sums [t][c], stride 260   12,480 B
    __shared__ float wsqL[256 * 17];  // wsq transposed [c][r]           17,408 B
    __shared__ float ybn[192], y1[192], mv[192];

    const int tid = threadIdx.x;
    const unsigned bid = blockIdx.x;
    const unsigned o = (bid & 7u) * 64u + (bid >> 3);   // bijective XCD chunk swizzle
    const unsigned n = o >> 2;
    const unsigned q = o & 3u;

    const v4f* x4 = (const v4f*)x + (size_t)n * 76800u + q * 75u;   // + c*300 + k
    v4f*       o4 = (v4f*)out     + (size_t)n * 76800u + q * 75u;
    float* gsb = (float*)buf;         // gate [c*12+t] aliases buf[0] after loop

    float acc = 0.f;                  // B1 accumulator (lanes 192..383)
    v4f tA[3], tB[3];                 // two in-flight chunk register sets

    auto issue = [&](int cg, v4f* t3) {       // issue chunk cg's loads
        #pragma unroll
        for (int it = 0; it < 3; ++it) {
            int s = it * 512 + tid;
            if (s < 1200) {
                int c = s / 75, k = s - c * 75;
                t3[it] = x4[(cg * 16 + c) * 300 + k];
            }
        }
    };
    auto writeL = [&](int cg, const v4f* t3) {  // regs -> LDS (auto vmcnt waits)
        #pragma unroll
        for (int it = 0; it < 3; ++it) {
            int s = it * 512 + tid;
            if (s < 1200) buf[cg & 1][s] = t3[it];
        }
    };
    auto reduceC = [&](int cg) {               // tid<192: frame sums of chunk cg
        int t = tid >> 4, cl = tid & 15;
        const float* bp = (const float*)buf[cg & 1] + cl * 300 + t * 25;
        float s = 0.f;
        #pragma unroll
        for (int v = 0; v < 25; ++v) s += bp[v];
        xb[t * 260 + cg * 16 + cl] = s;
    };
    auto accumB1 = [&](int cg) {               // 192<=tid<384: += chunk cg
        int u = tid - 192, t = u >> 4, r = u & 15;
        #pragma unroll
        for (int i2 = 0; i2 < 16; ++i2) {
            int c = cg * 16 + i2;
            acc += xb[t * 260 + c] * wsqL[c * 17 + r];   // xb broadcast, wsqL spread
        }
    };
    auto bar = [&]() {                 // barrier WITHOUT vmcnt drain
        asm volatile("s_waitcnt lgkmcnt(0)" ::: "memory");
        __builtin_amdgcn_s_barrier();
        __builtin_amdgcn_sched_barrier(0);
    };

    // ---- prologue: wsq -> LDS transposed; chunk0 staged; chunk1 in flight ----
    issue(0, tA);                                   // chunk 0 -> set A
    #pragma unroll
    for (int it = 0; it < 8; ++it) {
        int j = it * 512 + tid;                     // j = r*256 + c
        wsqL[(j & 255) * 17 + (j >> 8)] = wsq[j];
    }
    writeL(0, tA);
    issue(1, tB);                                   // chunk 1 -> set B
    bar();

    // ---- 16-chunk pipeline ----
    #pragma unroll
    for (int i = 0; i < 16; ++i) {
        if (i < 15) writeL(i + 1, (i & 1) ? tA : tB);   // set (i+1)&1
        if (i < 14) issue(i + 2, (i & 1) ? tB : tA);    // set (i+2)&1 == i&1
        if (tid < 192) reduceC(i);
        else if (tid < 384 && i > 0) accumB1(i - 1);
        bar();
    }

    // ---- epilogue: finish B1 + BN, conv1, diff, expand ----
    if (tid >= 192 && tid < 384) {
        accumB1(15);
        int u = tid - 192, r = u & 15;
        float sc = gamma[r] * rsqrtf(rvar[r] + 1e-5f);
        ybn[u] = acc * (0.04f * sc) + (bsq[r] * sc + beta[r] - rmean[r] * sc);
    }
    __syncthreads();
    if (tid < 192) {                                 // conv1
        int t = tid >> 4, s = tid & 15;
        float a = bc1[s];
        #pragma unroll
        for (int r = 0; r < 16; ++r) a += ybn[t * 16 + r] * wc1[s * 16 + r];
        y1[tid] = a;
    }
    __syncthreads();
    if (tid < 192) {                                 // temporal diff (4 whole segs)
        int t = tid >> 4;
        mv[tid] = ((t % 3) < 2) ? (y1[tid + 16] - ybn[tid]) : 0.f;
    }
    __syncthreads();
    {                                                // expand + sigmoid (c, t-half)
        int c = tid & 255, half = tid >> 8;
        float wexr[16];
        #pragma unroll
        for (int r = 0; r < 16; ++r) wexr[r] = wex[c * 16 + r];
        float be = bex[c];
        #pragma unroll
        for (int t = half * 6; t < half * 6 + 6; ++t) {
            float a = be;
            #pragma unroll
            for (int r = 0; r < 16; ++r) a += mv[t * 16 + r] * wexr[r];
            gsb[c * 12 + t] = 1.f / (1.f + expf(-a));
        }
    }
    __syncthreads();

    // ---- apply: re-read x (L3-hot), gate, NT float4 store (R17 verbatim) ----
    #pragma unroll 4
    for (int it = 0; it < 38; ++it) {
        int j = it * 512 + tid;
        if (j < 19200) {
            unsigned c = ((unsigned)j * 55926u) >> 22;   // j/75 (exact j<19200)
            int k = j - (int)c * 75;
            v4f v = x4[c * 300 + k];
            int m0  = k * 4;
            int t0  = (m0 * 41) >> 10;                   // m0/25 (exact m0<1024)
            int t3  = ((m0 + 3) * 41) >> 10;
            int rem = m0 - t0 * 25;
            float g0 = gsb[c * 12 + t0];
            float g3 = gsb[c * 12 + t3];
            v4f ov;
            ov.x = v.x * g0;
            ov.y = v.y * ((rem + 1 < 25) ? g0 : g3);
            ov.z = v.z * ((rem + 2 < 25) ? g0 : g3);
            ov.w = v.w * ((rem + 3 < 25) ? g0 : g3);
            __builtin_nontemporal_store(ov, &o4[c * 300 + k]);
        }
    }
}

extern "C" void kernel_launch(void* const* d_in, const int* in_sizes, int n_in,
                              void* d_out, int out_size, void* d_ws, size_t ws_size,
                              hipStream_t stream) {
    const float* x     = (const float*)d_in[0];
    const float* wsq   = (const float*)d_in[1];
    const float* bsq   = (const float*)d_in[2];
    const float* gamma = (const float*)d_in[3];
    const float* beta  = (const float*)d_in[4];
    const float* rmean = (const float*)d_in[5];
    const float* rvar  = (const float*)d_in[6];
    const float* wc1   = (const float*)d_in[7];
    const float* bc1   = (const float*)d_in[8];
    const float* wex   = (const float*)d_in[9];
    const float* bex   = (const float*)d_in[10];

    k_fused9<<<512, 512, 0, stream>>>(x, wsq, bsq, gamma, beta,
                                      rmean, rvar, wc1, bc1, wex, bex,
                                      (float*)d_out);
}

// Round 19
// 75.851 us; speedup vs baseline: 1.0227x; 1.0227x over previous
//
#include <hip/hip_runtime.h>

typedef float v4f __attribute__((ext_vector_type(4)));

// R18 + triple-buffered register staging: prefetch depth 2 chunks.
//   issue(i+3) -> writeL(i+1) distance = ~2 full iterations (>> HBM latency);
//   issue precedes the vmcnt-stalling writeL so the pipe refills before waiting.
//   Barriers drain lgkmcnt only (global loads stay in flight across barriers).
__global__ __launch_bounds__(512, 4) void k_fused10(
    const float* __restrict__ x,
    const float* __restrict__ wsq, const float* __restrict__ bsq,
    const float* __restrict__ gamma, const float* __restrict__ beta,
    const float* __restrict__ rmean, const float* __restrict__ rvar,
    const float* __restrict__ wc1, const float* __restrict__ bc1,
    const float* __restrict__ wex, const float* __restrict__ bex,
    float* __restrict__ out)
{
    __shared__ v4f   buf[2][1200];    // 38,400 B linear chunk stage (16 ch x 300 f)
    __shared__ float xb[12 * 260];    // frame sums [t][c], stride 260   12,480 B
    __shared__ float wsqL[256 * 17];  // wsq transposed [c][r]           17,408 B
    __shared__ float ybn[192], y1[192], mv[192];

    const int tid = threadIdx.x;
    const unsigned bid = blockIdx.x;
    const unsigned o = (bid & 7u) * 64u + (bid >> 3);   // bijective XCD chunk swizzle
    const unsigned n = o >> 2;
    const unsigned q = o & 3u;

    const v4f* x4 = (const v4f*)x + (size_t)n * 76800u + q * 75u;   // + c*300 + k
    v4f*       o4 = (v4f*)out     + (size_t)n * 76800u + q * 75u;
    float* gsb = (float*)buf;         // gate [c*12+t] aliases buf[0] after loop

    float acc = 0.f;                  // B1 accumulator (lanes 192..383)
    v4f sA[3], sB[3], sC[3];          // three in-flight chunk register sets

    auto issue = [&](int cg, v4f* t3) {       // issue chunk cg's loads
        #pragma unroll
        for (int it = 0; it < 3; ++it) {
            int s = it * 512 + tid;
            if (s < 1200) {
                int c = s / 75, k = s - c * 75;
                t3[it] = x4[(cg * 16 + c) * 300 + k];
            }
        }
    };
    auto writeL = [&](int cg, const v4f* t3) {  // regs -> LDS (vmcnt wait here)
        #pragma unroll
        for (int it = 0; it < 3; ++it) {
            int s = it * 512 + tid;
            if (s < 1200) buf[cg & 1][s] = t3[it];
        }
    };
    auto reduceC = [&](int cg) {               // tid<192: frame sums of chunk cg
        int t = tid >> 4, cl = tid & 15;
        const float* bp = (const float*)buf[cg & 1] + cl * 300 + t * 25;
        float s = 0.f;
        #pragma unroll
        for (int v = 0; v < 25; ++v) s += bp[v];
        xb[t * 260 + cg * 16 + cl] = s;
    };
    auto accumB1 = [&](int cg) {               // 192<=tid<384: += chunk cg
        int u = tid - 192, t = u >> 4, r = u & 15;
        #pragma unroll
        for (int i2 = 0; i2 < 16; ++i2) {
            int c = cg * 16 + i2;
            acc += xb[t * 260 + c] * wsqL[c * 17 + r];   // xb broadcast, wsqL spread
        }
    };
    auto bar = [&]() {                 // barrier WITHOUT vmcnt drain
        asm volatile("s_waitcnt lgkmcnt(0)" ::: "memory");
        __builtin_amdgcn_s_barrier();
        __builtin_amdgcn_sched_barrier(0);
    };

    // ---- prologue: chunks 0,1,2 in flight; wsq -> LDS transposed; stage 0 ----
    issue(0, sA);
    #pragma unroll
    for (int it = 0; it < 8; ++it) {
        int j = it * 512 + tid;                     // j = r*256 + c
        wsqL[(j & 255) * 17 + (j >> 8)] = wsq[j];
    }
    issue(1, sB);
    issue(2, sC);
    writeL(0, sA);
    bar();

    // ---- 16-chunk pipeline, depth-2 prefetch ----
    #pragma unroll
    for (int i = 0; i < 16; ++i) {
        v4f* sfree = (i % 3 == 0) ? sA : (i % 3 == 1) ? sB : sC;   // set[i%3]
        v4f* snext = (i % 3 == 0) ? sB : (i % 3 == 1) ? sC : sA;   // set[(i+1)%3]
        if (i < 13) issue(i + 3, sfree);            // refill BEFORE the vmcnt stall
        if (i < 15) writeL(i + 1, snext);           // loads from iter i-2: latency hidden
        if (tid < 192) reduceC(i);
        else if (tid < 384 && i > 0) accumB1(i - 1);
        bar();
    }

    // ---- epilogue: finish B1 + BN, conv1, diff, expand ----
    if (tid >= 192 && tid < 384) {
        accumB1(15);
        int u = tid - 192, r = u & 15;
        float sc = gamma[r] * rsqrtf(rvar[r] + 1e-5f);
        ybn[u] = acc * (0.04f * sc) + (bsq[r] * sc + beta[r] - rmean[r] * sc);
    }
    __syncthreads();
    if (tid < 192) {                                 // conv1
        int t = tid >> 4, s = tid & 15;
        float a = bc1[s];
        #pragma unroll
        for (int r = 0; r < 16; ++r) a += ybn[t * 16 + r] * wc1[s * 16 + r];
        y1[tid] = a;
    }
    __syncthreads();
    if (tid < 192) {                                 // temporal diff (4 whole segs)
        int t = tid >> 4;
        mv[tid] = ((t % 3) < 2) ? (y1[tid + 16] - ybn[tid]) : 0.f;
    }
    __syncthreads();
    {                                                // expand + sigmoid (c, t-half)
        int c = tid & 255, half = tid >> 8;
        float wexr[16];
        #pragma unroll
        for (int r = 0; r < 16; ++r) wexr[r] = wex[c * 16 + r];
        float be = bex[c];
        #pragma unroll
        for (int t = half * 6; t < half * 6 + 6; ++t) {
            float a = be;
            #pragma unroll
            for (int r = 0; r < 16; ++r) a += mv[t * 16 + r] * wexr[r];
            gsb[c * 12 + t] = 1.f / (1.f + expf(-a));
        }
    }
    __syncthreads();

    // ---- apply: re-read x (L3-hot), gate, NT float4 store (R17 verbatim) ----
    #pragma unroll 4
    for (int it = 0; it < 38; ++it) {
        int j = it * 512 + tid;
        if (j < 19200) {
            unsigned c = ((unsigned)j * 55926u) >> 22;   // j/75 (exact j<19200)
            int k = j - (int)c * 75;
            v4f v = x4[c * 300 + k];
            int m0  = k * 4;
            int t0  = (m0 * 41) >> 10;                   // m0/25 (exact m0<1024)
            int t3  = ((m0 + 3) * 41) >> 10;
            int rem = m0 - t0 * 25;
            float g0 = gsb[c * 12 + t0];
            float g3 = gsb[c * 12 + t3];
            v4f ov;
            ov.x = v.x * g0;
            ov.y = v.y * ((rem + 1 < 25) ? g0 : g3);
            ov.z = v.z * ((rem + 2 < 25) ? g0 : g3);
            ov.w = v.w * ((rem + 3 < 25) ? g0 : g3);
            __builtin_nontemporal_store(ov, &o4[c * 300 + k]);
        }
    }
}

extern "C" void kernel_launch(void* const* d_in, const int* in_sizes, int n_in,
                              void* d_out, int out_size, void* d_ws, size_t ws_size,
                              hipStream_t stream) {
    const float* x     = (const float*)d_in[0];
    const float* wsq   = (const float*)d_in[1];
    const float* bsq   = (const float*)d_in[2];
    const float* gamma = (const float*)d_in[3];
    const float* beta  = (const float*)d_in[4];
    const float* rmean = (const float*)d_in[5];
    const float* rvar  = (const float*)d_in[6];
    const float* wc1   = (const float*)d_in[7];
    const float* bc1   = (const float*)d_in[8];
    const float* wex   = (const float*)d_in[9];
    const float* bex   = (const float*)d_in[10];

    k_fused10<<<512, 512, 0, stream>>>(x, wsq, bsq, gamma, beta,
                                       rmean, rvar, wc1, bc1, wex, bex,
                                       (float*)d_out);
}